// Round 2
// baseline (3595.240 us; speedup 1.0000x reference)
//
#include <hip/hip_runtime.h>

// GeometricBlock fused kernel, MI355X gfx950.
// ws layout (needs ~52 MB):
//   [0,      32768)   W1p   bf16 packed  (64x256)
//   [32768,  229376)  W23p  bf16 packed  (384x256 = W_r2 ; W_s)
//   [229376, 491520)  Wqkp  bf16 packed  (256x512 = Wq | Wk)
//   [491520, 492544)  b23   f32 (b_r2 + b_s)
//   [524288, ...)     qk    bf16 [N][512] (q | k)

typedef short bf16x8 __attribute__((ext_vector_type(8)));
typedef float f32x4 __attribute__((ext_vector_type(4)));
typedef unsigned short u16;
typedef u16 u16x8 __attribute__((ext_vector_type(8)));
typedef u16 u16x4 __attribute__((ext_vector_type(4)));

__device__ __forceinline__ u16 f2bf(float f) {
  unsigned u = __builtin_bit_cast(unsigned, f);
  unsigned r = (u + 0x7FFFu + ((u >> 16) & 1u)) >> 16;  // round-nearest-even
  return (u16)r;
}
__device__ __forceinline__ float bf2f(u16 h) {
  return __builtin_bit_cast(float, ((unsigned)h) << 16);
}

// ---------------- kernel 0: pack weights to MFMA B-fragment order -----------
// B-frag layout for mfma_f32_16x16x32_bf16: lane l holds B[k=kf*32+(l>>4)*8+j][c=cf*16+(l&15)]
// packed at ((cf*KF + kf)*64 + l)*8 + j  -> one 16B load per lane per frag.
__global__ __launch_bounds__(256) void pack_kernel(
    const float* __restrict__ W1, const float* __restrict__ W2,
    const float* __restrict__ Wsp, const float* __restrict__ Wq,
    const float* __restrict__ Wk, const float* __restrict__ b2,
    const float* __restrict__ bs, u16* __restrict__ W1p,
    u16* __restrict__ W23p, u16* __restrict__ Wqkp, float* __restrict__ b23) {
  int t = blockIdx.x * 256 + threadIdx.x;
  if (t < 2048) {  // W1: K=64 (KF=2), C=256 (CF=16)
    int lane = t & 63, kf = (t >> 6) & 1, cf = t >> 7;
    int kb = kf * 32 + ((lane >> 4) << 3), c = cf * 16 + (lane & 15);
    u16x8 o;
#pragma unroll
    for (int j = 0; j < 8; j++) o[j] = f2bf(W1[(kb + j) * 256 + c]);
    *reinterpret_cast<u16x8*>(W1p + (((cf * 2 + kf) * 64 + lane) << 3)) = o;
  } else if (t < 14336) {  // W23: K=384 (KF=12), C=256
    int u = t - 2048;
    int lane = u & 63, f = u >> 6, kf = f % 12, cf = f / 12;
    int kb = kf * 32 + ((lane >> 4) << 3), c = cf * 16 + (lane & 15);
    u16x8 o;
#pragma unroll
    for (int j = 0; j < 8; j++) {
      int k = kb + j;
      float v = (k < 256) ? W2[k * 256 + c] : Wsp[(k - 256) * 256 + c];
      o[j] = f2bf(v);
    }
    *reinterpret_cast<u16x8*>(W23p + (((cf * 12 + kf) * 64 + lane) << 3)) = o;
  } else if (t < 30720) {  // Wqk: K=256 (KF=8), C=512 (CF=32)
    int u = t - 14336;
    int lane = u & 63, f = u >> 6, kf = f & 7, cf = f >> 3;
    int kb = kf * 32 + ((lane >> 4) << 3), c = cf * 16 + (lane & 15);
    u16x8 o;
#pragma unroll
    for (int j = 0; j < 8; j++) {
      int k = kb + j;
      float v = (c < 256) ? Wq[k * 256 + c] : Wk[k * 256 + (c - 256)];
      o[j] = f2bf(v);
    }
    *reinterpret_cast<u16x8*>(Wqkp + (((cf * 8 + kf) * 64 + lane) << 3)) = o;
  } else if (t < 30976) {
    int c = t - 30720;
    b23[c] = b2[c] + bs[c];
  }
}

// ---------------- kernel 1: qk[n] = node_feats[n] @ [Wq|Wk], bf16 out -------
__global__ __launch_bounds__(256) void node_qk_kernel(
    const float* __restrict__ nf, const u16* __restrict__ Wqkp,
    u16* __restrict__ qk, int N) {
  __shared__ u16 A[64 * 264];  // 64 rows x 256 bf16, +8 pad (row 528B, 16B-aligned)
  const int t = threadIdx.x;
  const int nb0 = blockIdx.x * 64;
#pragma unroll
  for (int p = 0; p < 16; p++) {
    int r = p * 4 + (t >> 6), c4 = t & 63;
    int row = nb0 + r;
    float4 v = make_float4(0.f, 0.f, 0.f, 0.f);
    if (row < N) v = *reinterpret_cast<const float4*>(nf + (size_t)row * 256 + c4 * 4);
    u16x4 o;
    o[0] = f2bf(v.x); o[1] = f2bf(v.y); o[2] = f2bf(v.z); o[3] = f2bf(v.w);
    *reinterpret_cast<u16x4*>(&A[r * 264 + c4 * 4]) = o;
  }
  __syncthreads();
  const int lane = t & 63, wv = t >> 6;
  const int l15 = lane & 15, lhi = lane >> 4;
  for (int nh = 0; nh < 2; nh++) {  // two 64-col halves to cap VGPR
    const int colbase = wv * 128 + nh * 64;
    f32x4 acc[4][4];
#pragma unroll
    for (int m = 0; m < 4; m++)
#pragma unroll
      for (int n = 0; n < 4; n++) acc[m][n] = f32x4{0.f, 0.f, 0.f, 0.f};
#pragma unroll
    for (int kf = 0; kf < 8; kf++) {
      bf16x8 a[4];
#pragma unroll
      for (int m = 0; m < 4; m++)
        a[m] = *reinterpret_cast<const bf16x8*>(&A[(m * 16 + l15) * 264 + kf * 32 + lhi * 8]);
#pragma unroll
      for (int n = 0; n < 4; n++) {
        int cf = (colbase >> 4) + n;
        bf16x8 b = *reinterpret_cast<const bf16x8*>(Wqkp + (((cf * 8 + kf) * 64 + lane) << 3));
#pragma unroll
        for (int m = 0; m < 4; m++)
          acc[m][n] = __builtin_amdgcn_mfma_f32_16x16x32_bf16(a[m], b, acc[m][n], 0, 0, 0);
      }
    }
    // D layout: row=(l>>4)*4+j, col=l&15 (m89-verified)
#pragma unroll
    for (int m = 0; m < 4; m++) {
      int row = nb0 + m * 16 + lhi * 4;
#pragma unroll
      for (int n = 0; n < 4; n++) {
        int col = colbase + n * 16 + l15;
#pragma unroll
        for (int j = 0; j < 4; j++) {
          if (row + j < N) qk[(size_t)(row + j) * 512 + col] = f2bf(acc[m][n][j]);
        }
      }
    }
  }
}

// ---------------- kernel 2: fused edge pipeline -----------------------------
__global__ __launch_bounds__(256) void edge_fused_kernel(
    const float* __restrict__ edge_sh, const float* __restrict__ edge_feats,
    const float* __restrict__ chi_s, const float* __restrict__ cutoffs,
    const int* __restrict__ senders, const int* __restrict__ receivers,
    const u16* __restrict__ W1p, const u16* __restrict__ W23p,
    const float* __restrict__ b1, const float* __restrict__ b23,
    const u16* __restrict__ qk, float* __restrict__ out, int E) {
  __shared__ u16 H[64 * 264];     // hidden (bf16), later w (bf16); row 528B
  __shared__ u16 Abuf[64 * 136];  // ef tile (stride 72) then chi tile (stride 136)
  __shared__ float alpha_s[64 * 32];
  __shared__ int recv_s[64];
  __shared__ int send_s[64];
  __shared__ float cut_s[64];

  const int t = threadIdx.x;
  const int e0 = blockIdx.x * 64;
  const int lane = t & 63, wv = t >> 6, l15 = lane & 15, lhi = lane >> 4;

  if (t < 64) {
    int e = e0 + t;
    bool v = e < E;
    recv_s[t] = v ? receivers[e] : 0;
    send_s[t] = v ? senders[e] : 0;
    cut_s[t] = v ? cutoffs[e] : 0.f;
  }
  // stage edge_feats [64][64] f32 -> bf16 LDS
#pragma unroll
  for (int p = 0; p < 4; p++) {
    int r = p * 16 + (t >> 4), c4 = t & 15;
    int e = e0 + r;
    float4 v = make_float4(0.f, 0.f, 0.f, 0.f);
    if (e < E) v = *reinterpret_cast<const float4*>(edge_feats + (size_t)e * 64 + c4 * 4);
    u16x4 o;
    o[0] = f2bf(v.x); o[1] = f2bf(v.y); o[2] = f2bf(v.z); o[3] = f2bf(v.w);
    *reinterpret_cast<u16x4*>(&Abuf[r * 72 + c4 * 4]) = o;
  }
  __syncthreads();

  f32x4 acc[4][4];
  // ---- GEMM1: hidden = silu(ef @ W1 + b1), wave owns cols [wv*64, wv*64+64)
#pragma unroll
  for (int m = 0; m < 4; m++)
#pragma unroll
    for (int n = 0; n < 4; n++) acc[m][n] = f32x4{0.f, 0.f, 0.f, 0.f};
#pragma unroll
  for (int kf = 0; kf < 2; kf++) {
    bf16x8 a[4];
#pragma unroll
    for (int m = 0; m < 4; m++)
      a[m] = *reinterpret_cast<const bf16x8*>(&Abuf[(m * 16 + l15) * 72 + kf * 32 + lhi * 8]);
#pragma unroll
    for (int n = 0; n < 4; n++) {
      int cf = wv * 4 + n;
      bf16x8 b = *reinterpret_cast<const bf16x8*>(W1p + (((cf * 2 + kf) * 64 + lane) << 3));
#pragma unroll
      for (int m = 0; m < 4; m++)
        acc[m][n] = __builtin_amdgcn_mfma_f32_16x16x32_bf16(a[m], b, acc[m][n], 0, 0, 0);
    }
  }
  {
    float bv[4];
#pragma unroll
    for (int n = 0; n < 4; n++) bv[n] = b1[wv * 64 + n * 16 + l15];
#pragma unroll
    for (int m = 0; m < 4; m++)
#pragma unroll
      for (int n = 0; n < 4; n++)
#pragma unroll
        for (int j = 0; j < 4; j++) {
          float x = acc[m][n][j] + bv[n];
          x = x / (1.f + __expf(-x));  // silu
          H[(m * 16 + lhi * 4 + j) * 264 + wv * 64 + n * 16 + l15] = f2bf(x);
        }
  }
  __syncthreads();
  // stage chi_scalar [64][128] -> bf16 LDS (reuse Abuf)
#pragma unroll
  for (int p = 0; p < 8; p++) {
    int r = p * 8 + (t >> 5), c4 = t & 31;
    int e = e0 + r;
    float4 v = make_float4(0.f, 0.f, 0.f, 0.f);
    if (e < E) v = *reinterpret_cast<const float4*>(chi_s + (size_t)e * 128 + c4 * 4);
    u16x4 o;
    o[0] = f2bf(v.x); o[1] = f2bf(v.y); o[2] = f2bf(v.z); o[3] = f2bf(v.w);
    *reinterpret_cast<u16x4*>(&Abuf[r * 136 + c4 * 4]) = o;
  }
  __syncthreads();
  // ---- GEMM2 (hidden, K=256) + GEMM3 (chi, K=128): w = . @ W23 + b23
#pragma unroll
  for (int m = 0; m < 4; m++)
#pragma unroll
    for (int n = 0; n < 4; n++) acc[m][n] = f32x4{0.f, 0.f, 0.f, 0.f};
#pragma unroll
  for (int kf = 0; kf < 8; kf++) {
    bf16x8 a[4];
#pragma unroll
    for (int m = 0; m < 4; m++)
      a[m] = *reinterpret_cast<const bf16x8*>(&H[(m * 16 + l15) * 264 + kf * 32 + lhi * 8]);
#pragma unroll
    for (int n = 0; n < 4; n++) {
      int cf = wv * 4 + n;
      bf16x8 b = *reinterpret_cast<const bf16x8*>(W23p + (((cf * 12 + kf) * 64 + lane) << 3));
#pragma unroll
      for (int m = 0; m < 4; m++)
        acc[m][n] = __builtin_amdgcn_mfma_f32_16x16x32_bf16(a[m], b, acc[m][n], 0, 0, 0);
    }
  }
#pragma unroll
  for (int kf = 0; kf < 4; kf++) {
    bf16x8 a[4];
#pragma unroll
    for (int m = 0; m < 4; m++)
      a[m] = *reinterpret_cast<const bf16x8*>(&Abuf[(m * 16 + l15) * 136 + kf * 32 + lhi * 8]);
#pragma unroll
    for (int n = 0; n < 4; n++) {
      int cf = wv * 4 + n;
      bf16x8 b = *reinterpret_cast<const bf16x8*>(W23p + (((cf * 12 + 8 + kf) * 64 + lane) << 3));
#pragma unroll
      for (int m = 0; m < 4; m++)
        acc[m][n] = __builtin_amdgcn_mfma_f32_16x16x32_bf16(a[m], b, acc[m][n], 0, 0, 0);
    }
  }
  __syncthreads();  // all H(hidden) reads done -> safe to overwrite with w
  {
    float bv[4];
#pragma unroll
    for (int n = 0; n < 4; n++) bv[n] = b23[wv * 64 + n * 16 + l15];
#pragma unroll
    for (int m = 0; m < 4; m++)
#pragma unroll
      for (int n = 0; n < 4; n++)
#pragma unroll
        for (int j = 0; j < 4; j++)
          H[(m * 16 + lhi * 4 + j) * 264 + wv * 64 + n * 16 + l15] =
              f2bf(acc[m][n][j] + bv[n]);
  }
  __syncthreads();
  // ---- alpha[e][h] = sum_d q*w*k * cutoff/sqrt(8)/10
  {
    int e = t >> 2, h4 = t & 3;
    const u16* qrow = qk + (size_t)recv_s[e] * 512;
    const u16* krow = qk + (size_t)send_s[e] * 512 + 256;
    float sc = cut_s[e] * 0.035355339059327376f;  // 0.1/sqrt(8)
#pragma unroll
    for (int i = 0; i < 8; i++) {
      int h = i * 4 + h4;  // threads 0..3 of a quad read contiguous 64B of qk
      u16x8 q8 = *reinterpret_cast<const u16x8*>(qrow + h * 8);
      u16x8 k8 = *reinterpret_cast<const u16x8*>(krow + h * 8);
      u16x8 w8 = *reinterpret_cast<const u16x8*>(&H[e * 264 + h * 8]);
      float s = 0.f;
#pragma unroll
      for (int d = 0; d < 8; d++) s += bf2f(q8[d]) * bf2f(w8[d]) * bf2f(k8[d]);
      alpha_s[e * 32 + h] = s * sc;
    }
  }
  __syncthreads();
  // ---- msg = edge_sh * repeat(alpha over [1,3,5,7]); scatter to out[recv]
  {
    int e = t >> 2, ee = e0 + e, q4 = t & 3;
    if (ee < E) {
      const float* shp = edge_sh + (size_t)ee * 128 + q4 * 32;
      float* op = out + (size_t)recv_s[e] * 128 + q4 * 32;
      const float* arow = alpha_s + e * 32;
#pragma unroll
      for (int i = 0; i < 8; i++) {
        float4 sh = *reinterpret_cast<const float4*>(shp + i * 4);
        float vals[4] = {sh.x, sh.y, sh.z, sh.w};
        int cb = q4 * 32 + i * 4;
#pragma unroll
        for (int d = 0; d < 4; d++) {
          int c = cb + d;
          int j = c & 15;
          int hd = ((c >> 4) << 2) + ((j > 0) + (j > 3) + (j > 8));  // irrep of [1,3,5,7]
          atomicAdd(op + i * 4 + d, vals[d] * arow[hd]);
        }
      }
    }
  }
}

extern "C" void kernel_launch(void* const* d_in, const int* in_sizes, int n_in,
                              void* d_out, int out_size, void* d_ws, size_t ws_size,
                              hipStream_t stream) {
  const float* edge_sh = (const float*)d_in[0];
  const float* node_feats = (const float*)d_in[1];
  const float* edge_feats = (const float*)d_in[2];
  const float* chi_s = (const float*)d_in[3];
  const float* cutoffs = (const float*)d_in[4];
  const int* senders = (const int*)d_in[5];
  const int* receivers = (const int*)d_in[6];
  const float* W1 = (const float*)d_in[7];
  const float* b1 = (const float*)d_in[8];
  const float* W2 = (const float*)d_in[9];
  const float* b2 = (const float*)d_in[10];
  const float* Wsp = (const float*)d_in[11];
  const float* bs = (const float*)d_in[12];
  const float* Wq = (const float*)d_in[13];
  const float* Wk = (const float*)d_in[14];

  const int E = in_sizes[4];
  const int N = in_sizes[1] / 256;

  char* ws = (char*)d_ws;
  u16* W1p = (u16*)(ws + 0);
  u16* W23p = (u16*)(ws + 32768);
  u16* Wqkp = (u16*)(ws + 229376);
  float* b23 = (float*)(ws + 491520);
  u16* qk = (u16*)(ws + 524288);  // N*512 bf16 = 51.2 MB

  (void)hipMemsetAsync(d_out, 0, (size_t)out_size * sizeof(float), stream);
  pack_kernel<<<121, 256, 0, stream>>>(W1, W2, Wsp, Wq, Wk, b2, bs, W1p, W23p, Wqkp, b23);
  node_qk_kernel<<<(N + 63) / 64, 256, 0, stream>>>(node_feats, Wqkp, qk, N);
  edge_fused_kernel<<<(E + 63) / 64, 256, 0, stream>>>(
      edge_sh, edge_feats, chi_s, cutoffs, senders, receivers, W1p, W23p, b1,
      b23, qk, (float*)d_out, E);
}

// Round 4
// 528.863 us; speedup vs baseline: 6.7981x; 6.7981x over previous
//
#include <hip/hip_runtime.h>

// GeometricBlock, MI355X gfx950. Atomic-free scatter via CSR.
// ws layout (runtime-computed; ~118 MB with f32 alpha, ~86 MB bf16 fallback):
//   W1p bf16 (64x256) | W23p bf16 (384x256) | Wqkp bf16 (256x512) | b23 f32
//   qk bf16 [N][512] | alpha [E][32] (f32 or bf16) | CSR: counts/off/cursor/eid

typedef short bf16x8 __attribute__((ext_vector_type(8)));
typedef float f32x4 __attribute__((ext_vector_type(4)));
typedef unsigned short u16;
typedef u16 u16x8 __attribute__((ext_vector_type(8)));
typedef u16 u16x4 __attribute__((ext_vector_type(4)));

__device__ __forceinline__ u16 f2bf(float f) {
  unsigned u = __builtin_bit_cast(unsigned, f);
  unsigned r = (u + 0x7FFFu + ((u >> 16) & 1u)) >> 16;  // round-nearest-even
  return (u16)r;
}
__device__ __forceinline__ float bf2f(u16 h) {
  return __builtin_bit_cast(float, ((unsigned)h) << 16);
}

// ---------------- pack weights to MFMA B-fragment order ---------------------
__global__ __launch_bounds__(256) void pack_kernel(
    const float* __restrict__ W1, const float* __restrict__ W2,
    const float* __restrict__ Wsp, const float* __restrict__ Wq,
    const float* __restrict__ Wk, const float* __restrict__ b2,
    const float* __restrict__ bs, u16* __restrict__ W1p,
    u16* __restrict__ W23p, u16* __restrict__ Wqkp, float* __restrict__ b23) {
  int t = blockIdx.x * 256 + threadIdx.x;
  if (t < 2048) {  // W1: K=64 (KF=2), C=256 (CF=16)
    int lane = t & 63, kf = (t >> 6) & 1, cf = t >> 7;
    int kb = kf * 32 + ((lane >> 4) << 3), c = cf * 16 + (lane & 15);
    u16x8 o;
#pragma unroll
    for (int j = 0; j < 8; j++) o[j] = f2bf(W1[(kb + j) * 256 + c]);
    *reinterpret_cast<u16x8*>(W1p + (((cf * 2 + kf) * 64 + lane) << 3)) = o;
  } else if (t < 14336) {  // W23: K=384 (KF=12), C=256
    int u = t - 2048;
    int lane = u & 63, f = u >> 6, kf = f % 12, cf = f / 12;
    int kb = kf * 32 + ((lane >> 4) << 3), c = cf * 16 + (lane & 15);
    u16x8 o;
#pragma unroll
    for (int j = 0; j < 8; j++) {
      int k = kb + j;
      float v = (k < 256) ? W2[k * 256 + c] : Wsp[(k - 256) * 256 + c];
      o[j] = f2bf(v);
    }
    *reinterpret_cast<u16x8*>(W23p + (((cf * 12 + kf) * 64 + lane) << 3)) = o;
  } else if (t < 30720) {  // Wqk: K=256 (KF=8), C=512 (CF=32)
    int u = t - 14336;
    int lane = u & 63, f = u >> 6, kf = f & 7, cf = f >> 3;
    int kb = kf * 32 + ((lane >> 4) << 3), c = cf * 16 + (lane & 15);
    u16x8 o;
#pragma unroll
    for (int j = 0; j < 8; j++) {
      int k = kb + j;
      float v = (c < 256) ? Wq[k * 256 + c] : Wk[k * 256 + (c - 256)];
      o[j] = f2bf(v);
    }
    *reinterpret_cast<u16x8*>(Wqkp + (((cf * 8 + kf) * 64 + lane) << 3)) = o;
  } else if (t < 30976) {
    int c = t - 30720;
    b23[c] = b2[c] + bs[c];
  }
}

// ---------------- qk[n] = node_feats[n] @ [Wq|Wk], bf16 out -----------------
__global__ __launch_bounds__(256) void node_qk_kernel(
    const float* __restrict__ nf, const u16* __restrict__ Wqkp,
    u16* __restrict__ qk, int N) {
  __shared__ u16 A[64 * 264];
  const int t = threadIdx.x;
  const int nb0 = blockIdx.x * 64;
#pragma unroll
  for (int p = 0; p < 16; p++) {
    int r = p * 4 + (t >> 6), c4 = t & 63;
    int row = nb0 + r;
    float4 v = make_float4(0.f, 0.f, 0.f, 0.f);
    if (row < N) v = *reinterpret_cast<const float4*>(nf + (size_t)row * 256 + c4 * 4);
    u16x4 o;
    o[0] = f2bf(v.x); o[1] = f2bf(v.y); o[2] = f2bf(v.z); o[3] = f2bf(v.w);
    *reinterpret_cast<u16x4*>(&A[r * 264 + c4 * 4]) = o;
  }
  __syncthreads();
  const int lane = t & 63, wv = t >> 6;
  const int l15 = lane & 15, lhi = lane >> 4;
  for (int nh = 0; nh < 2; nh++) {
    const int colbase = wv * 128 + nh * 64;
    f32x4 acc[4][4];
#pragma unroll
    for (int m = 0; m < 4; m++)
#pragma unroll
      for (int n = 0; n < 4; n++) acc[m][n] = f32x4{0.f, 0.f, 0.f, 0.f};
#pragma unroll
    for (int kf = 0; kf < 8; kf++) {
      bf16x8 a[4];
#pragma unroll
      for (int m = 0; m < 4; m++)
        a[m] = *reinterpret_cast<const bf16x8*>(&A[(m * 16 + l15) * 264 + kf * 32 + lhi * 8]);
#pragma unroll
      for (int n = 0; n < 4; n++) {
        int cf = (colbase >> 4) + n;
        bf16x8 b = *reinterpret_cast<const bf16x8*>(Wqkp + (((cf * 8 + kf) * 64 + lane) << 3));
#pragma unroll
        for (int m = 0; m < 4; m++)
          acc[m][n] = __builtin_amdgcn_mfma_f32_16x16x32_bf16(a[m], b, acc[m][n], 0, 0, 0);
      }
    }
#pragma unroll
    for (int m = 0; m < 4; m++) {
      int row = nb0 + m * 16 + lhi * 4;
#pragma unroll
      for (int n = 0; n < 4; n++) {
        int col = colbase + n * 16 + l15;
#pragma unroll
        for (int j = 0; j < 4; j++) {
          if (row + j < N) qk[(size_t)(row + j) * 512 + col] = f2bf(acc[m][n][j]);
        }
      }
    }
  }
}

// ---------------- edge alpha: GEMMs + q.w.k -> alpha[E,32] ------------------
__global__ __launch_bounds__(256) void edge_alpha_kernel(
    const float* __restrict__ edge_feats, const float* __restrict__ chi_s,
    const float* __restrict__ cutoffs, const int* __restrict__ senders,
    const int* __restrict__ receivers, const u16* __restrict__ W1p,
    const u16* __restrict__ W23p, const float* __restrict__ b1,
    const float* __restrict__ b23, const u16* __restrict__ qk,
    void* __restrict__ alpha_out, int alpha_f32, int E) {
  __shared__ u16 H[64 * 264];    // hidden bf16, later w bf16
  __shared__ u16 Abuf[64 * 72];  // ef / chi-half tile, stride 72
  __shared__ float alpha_s[64 * 32];
  __shared__ int recv_s[64];
  __shared__ int send_s[64];
  __shared__ float cut_s[64];

  const int t = threadIdx.x;
  const int e0 = blockIdx.x * 64;
  const int lane = t & 63, wv = t >> 6, l15 = lane & 15, lhi = lane >> 4;

  if (t < 64) {
    int e = e0 + t;
    bool v = e < E;
    recv_s[t] = v ? receivers[e] : 0;
    send_s[t] = v ? senders[e] : 0;
    cut_s[t] = v ? cutoffs[e] : 0.f;
  }
  // stage edge_feats [64][64] f32 -> bf16
#pragma unroll
  for (int p = 0; p < 4; p++) {
    int r = p * 16 + (t >> 4), c4 = t & 15;
    int e = e0 + r;
    float4 v = make_float4(0.f, 0.f, 0.f, 0.f);
    if (e < E) v = *reinterpret_cast<const float4*>(edge_feats + (size_t)e * 64 + c4 * 4);
    u16x4 o;
    o[0] = f2bf(v.x); o[1] = f2bf(v.y); o[2] = f2bf(v.z); o[3] = f2bf(v.w);
    *reinterpret_cast<u16x4*>(&Abuf[r * 72 + c4 * 4]) = o;
  }
  __syncthreads();

  f32x4 acc[4][4];
  // ---- GEMM1: hidden = silu(ef @ W1 + b1)
#pragma unroll
  for (int m = 0; m < 4; m++)
#pragma unroll
    for (int n = 0; n < 4; n++) acc[m][n] = f32x4{0.f, 0.f, 0.f, 0.f};
#pragma unroll
  for (int kf = 0; kf < 2; kf++) {
    bf16x8 a[4];
#pragma unroll
    for (int m = 0; m < 4; m++)
      a[m] = *reinterpret_cast<const bf16x8*>(&Abuf[(m * 16 + l15) * 72 + kf * 32 + lhi * 8]);
#pragma unroll
    for (int n = 0; n < 4; n++) {
      int cf = wv * 4 + n;
      bf16x8 b = *reinterpret_cast<const bf16x8*>(W1p + (((cf * 2 + kf) * 64 + lane) << 3));
#pragma unroll
      for (int m = 0; m < 4; m++)
        acc[m][n] = __builtin_amdgcn_mfma_f32_16x16x32_bf16(a[m], b, acc[m][n], 0, 0, 0);
    }
  }
  {
    float bv[4];
#pragma unroll
    for (int n = 0; n < 4; n++) bv[n] = b1[wv * 64 + n * 16 + l15];
#pragma unroll
    for (int m = 0; m < 4; m++)
#pragma unroll
      for (int n = 0; n < 4; n++)
#pragma unroll
        for (int j = 0; j < 4; j++) {
          float x = acc[m][n][j] + bv[n];
          x = x / (1.f + __expf(-x));  // silu
          H[(m * 16 + lhi * 4 + j) * 264 + wv * 64 + n * 16 + l15] = f2bf(x);
        }
  }
  __syncthreads();
  // stage chi half0 (cols 0..63)
#pragma unroll
  for (int p = 0; p < 4; p++) {
    int r = p * 16 + (t >> 4), c4 = t & 15;
    int e = e0 + r;
    float4 v = make_float4(0.f, 0.f, 0.f, 0.f);
    if (e < E) v = *reinterpret_cast<const float4*>(chi_s + (size_t)e * 128 + c4 * 4);
    u16x4 o;
    o[0] = f2bf(v.x); o[1] = f2bf(v.y); o[2] = f2bf(v.z); o[3] = f2bf(v.w);
    *reinterpret_cast<u16x4*>(&Abuf[r * 72 + c4 * 4]) = o;
  }
  __syncthreads();
  // ---- GEMM2 (hidden K=256) + GEMM3 half0 (chi k 0..63)
#pragma unroll
  for (int m = 0; m < 4; m++)
#pragma unroll
    for (int n = 0; n < 4; n++) acc[m][n] = f32x4{0.f, 0.f, 0.f, 0.f};
#pragma unroll
  for (int kf = 0; kf < 8; kf++) {
    bf16x8 a[4];
#pragma unroll
    for (int m = 0; m < 4; m++)
      a[m] = *reinterpret_cast<const bf16x8*>(&H[(m * 16 + l15) * 264 + kf * 32 + lhi * 8]);
#pragma unroll
    for (int n = 0; n < 4; n++) {
      int cf = wv * 4 + n;
      bf16x8 b = *reinterpret_cast<const bf16x8*>(W23p + (((cf * 12 + kf) * 64 + lane) << 3));
#pragma unroll
      for (int m = 0; m < 4; m++)
        acc[m][n] = __builtin_amdgcn_mfma_f32_16x16x32_bf16(a[m], b, acc[m][n], 0, 0, 0);
    }
  }
#pragma unroll
  for (int kf = 0; kf < 2; kf++) {
    bf16x8 a[4];
#pragma unroll
    for (int m = 0; m < 4; m++)
      a[m] = *reinterpret_cast<const bf16x8*>(&Abuf[(m * 16 + l15) * 72 + kf * 32 + lhi * 8]);
#pragma unroll
    for (int n = 0; n < 4; n++) {
      int cf = wv * 4 + n;
      bf16x8 b = *reinterpret_cast<const bf16x8*>(W23p + (((cf * 12 + 8 + kf) * 64 + lane) << 3));
#pragma unroll
      for (int m = 0; m < 4; m++)
        acc[m][n] = __builtin_amdgcn_mfma_f32_16x16x32_bf16(a[m], b, acc[m][n], 0, 0, 0);
    }
  }
  __syncthreads();
  // stage chi half1 (cols 64..127)
#pragma unroll
  for (int p = 0; p < 4; p++) {
    int r = p * 16 + (t >> 4), c4 = t & 15;
    int e = e0 + r;
    float4 v = make_float4(0.f, 0.f, 0.f, 0.f);
    if (e < E) v = *reinterpret_cast<const float4*>(chi_s + (size_t)e * 128 + 64 + c4 * 4);
    u16x4 o;
    o[0] = f2bf(v.x); o[1] = f2bf(v.y); o[2] = f2bf(v.z); o[3] = f2bf(v.w);
    *reinterpret_cast<u16x4*>(&Abuf[r * 72 + c4 * 4]) = o;
  }
  __syncthreads();
  // ---- GEMM3 half1 (chi k 64..127)
#pragma unroll
  for (int kf = 0; kf < 2; kf++) {
    bf16x8 a[4];
#pragma unroll
    for (int m = 0; m < 4; m++)
      a[m] = *reinterpret_cast<const bf16x8*>(&Abuf[(m * 16 + l15) * 72 + kf * 32 + lhi * 8]);
#pragma unroll
    for (int n = 0; n < 4; n++) {
      int cf = wv * 4 + n;
      bf16x8 b = *reinterpret_cast<const bf16x8*>(W23p + (((cf * 12 + 10 + kf) * 64 + lane) << 3));
#pragma unroll
      for (int m = 0; m < 4; m++)
        acc[m][n] = __builtin_amdgcn_mfma_f32_16x16x32_bf16(a[m], b, acc[m][n], 0, 0, 0);
    }
  }
  __syncthreads();  // all H(hidden) reads done -> safe to overwrite with w
  {
    float bv[4];
#pragma unroll
    for (int n = 0; n < 4; n++) bv[n] = b23[wv * 64 + n * 16 + l15];
#pragma unroll
    for (int m = 0; m < 4; m++)
#pragma unroll
      for (int n = 0; n < 4; n++)
#pragma unroll
        for (int j = 0; j < 4; j++)
          H[(m * 16 + lhi * 4 + j) * 264 + wv * 64 + n * 16 + l15] =
              f2bf(acc[m][n][j] + bv[n]);
  }
  __syncthreads();
  // ---- alpha[e][h] = sum_d q*w*k * cutoff * (1/sqrt(8)) * (1/10 neighbors)
  {
    int e = t >> 2, h4 = t & 3;
    const u16* qrow = qk + (size_t)recv_s[e] * 512;
    const u16* krow = qk + (size_t)send_s[e] * 512 + 256;
    float sc = cut_s[e] * 0.035355339059327376f;  // (1/sqrt(8))*(1/10)
#pragma unroll
    for (int i = 0; i < 8; i++) {
      int h = i * 4 + h4;
      u16x8 q8 = *reinterpret_cast<const u16x8*>(qrow + h * 8);
      u16x8 k8 = *reinterpret_cast<const u16x8*>(krow + h * 8);
      u16x8 w8 = *reinterpret_cast<const u16x8*>(&H[e * 264 + h * 8]);
      float s = 0.f;
#pragma unroll
      for (int d = 0; d < 8; d++) s += bf2f(q8[d]) * bf2f(w8[d]) * bf2f(k8[d]);
      alpha_s[e * 32 + h] = s * sc;
    }
  }
  __syncthreads();
  // coalesced alpha writeout (8 values per thread, contiguous)
  {
    int e = e0 + (t >> 2);
    if (e < E) {
      if (alpha_f32) {
        float4* dst = reinterpret_cast<float4*>((float*)alpha_out + (size_t)e0 * 32);
        const float4* src = reinterpret_cast<const float4*>(alpha_s);
        dst[t * 2] = src[t * 2];
        dst[t * 2 + 1] = src[t * 2 + 1];
      } else {
        u16x8 o;
#pragma unroll
        for (int j = 0; j < 8; j++) o[j] = f2bf(alpha_s[t * 8 + j]);
        reinterpret_cast<u16x8*>((u16*)alpha_out + (size_t)e0 * 32)[t] = o;
      }
    }
  }
}

// ---------------- CSR build ------------------------------------------------
__global__ __launch_bounds__(256) void hist_kernel(const int* __restrict__ recv,
                                                   int* __restrict__ counts, int E) {
  int e = blockIdx.x * 256 + threadIdx.x;
  if (e < E) atomicAdd(&counts[recv[e]], 1);
}

// in-place: counts -> per-element exclusive partial (within 1024-chunk); bsum[b]=chunk total
__global__ __launch_bounds__(256) void scan_block_kernel(int* __restrict__ counts,
                                                         int* __restrict__ bsum, int N) {
  __shared__ int tmp[256];
  int t = threadIdx.x;
  int base = blockIdx.x * 1024 + t * 4;
  int v[4], p[4], tot = 0;
#pragma unroll
  for (int j = 0; j < 4; j++) {
    int n = base + j;
    v[j] = (n < N) ? counts[n] : 0;
    p[j] = tot;
    tot += v[j];
  }
  tmp[t] = tot;
  __syncthreads();
  for (int s = 1; s < 256; s <<= 1) {
    int a = (t >= s) ? tmp[t - s] : 0;
    __syncthreads();
    tmp[t] += a;
    __syncthreads();
  }
  int excl = tmp[t] - tot;
#pragma unroll
  for (int j = 0; j < 4; j++) {
    int n = base + j;
    if (n < N) counts[n] = excl + p[j];
  }
  if (t == 255) bsum[blockIdx.x] = tmp[255];
}

__global__ void scan_top_kernel(const int* __restrict__ bsum, int* __restrict__ boff, int nb) {
  if (threadIdx.x == 0 && blockIdx.x == 0) {
    int ex = 0;
    for (int b = 0; b < nb; b++) {
      boff[b] = ex;
      ex += bsum[b];
    }
  }
}

__global__ __launch_bounds__(256) void finalize_kernel(
    const int* __restrict__ partial, const int* __restrict__ boff,
    int* __restrict__ off, int* __restrict__ cursor, int N, int E) {
  int n = blockIdx.x * 256 + threadIdx.x;
  if (n < N) {
    int o = partial[n] + boff[n >> 10];
    off[n] = o;
    cursor[n] = o;
  }
  if (n == 0) off[N] = E;
}

__global__ __launch_bounds__(256) void fill_kernel(const int* __restrict__ recv,
                                                   int* __restrict__ cursor,
                                                   int* __restrict__ eid, int E) {
  int e = blockIdx.x * 256 + threadIdx.x;
  if (e < E) {
    int pos = atomicAdd(&cursor[recv[e]], 1);
    eid[pos] = e;
  }
}

// ---------------- gather: out[n] = sum_{e in CSR(n)} sh[e] * alpha[e,hd] ----
__global__ __launch_bounds__(256) void gather_out_kernel(
    const float* __restrict__ edge_sh, const void* __restrict__ alpha,
    const int* __restrict__ off, const int* __restrict__ eid,
    float* __restrict__ out, int N, int alpha_f32) {
  int wv = threadIdx.x >> 6, lane = threadIdx.x & 63;
  int n = blockIdx.x * 4 + wv;
  if (n >= N) return;
  int beg = off[n], end = off[n + 1];
  int c0 = lane * 2;
  int j0 = c0 & 15, j1 = (c0 + 1) & 15;
  int hd0 = ((c0 >> 4) << 2) + (j0 > 0) + (j0 > 3) + (j0 > 8);
  int hd1 = (((c0 + 1) >> 4) << 2) + (j1 > 0) + (j1 > 3) + (j1 > 8);
  const float* af = (const float*)alpha;
  const u16* ah = (const u16*)alpha;
  float a0 = 0.f, a1 = 0.f;
  for (int i = beg; i < end; i++) {
    int e = eid[i];
    float2 s = *reinterpret_cast<const float2*>(edge_sh + (size_t)e * 128 + c0);
    float va0, va1;
    if (alpha_f32) {
      va0 = af[(size_t)e * 32 + hd0];
      va1 = af[(size_t)e * 32 + hd1];
    } else {
      va0 = bf2f(ah[(size_t)e * 32 + hd0]);
      va1 = bf2f(ah[(size_t)e * 32 + hd1]);
    }
    a0 += s.x * va0;
    a1 += s.y * va1;
  }
  *reinterpret_cast<float2*>(out + (size_t)n * 128 + c0) = make_float2(a0, a1);
}

static inline size_t align64(size_t x) { return (x + 63) & ~(size_t)63; }

extern "C" void kernel_launch(void* const* d_in, const int* in_sizes, int n_in,
                              void* d_out, int out_size, void* d_ws, size_t ws_size,
                              hipStream_t stream) {
  const float* edge_sh = (const float*)d_in[0];
  const float* node_feats = (const float*)d_in[1];
  const float* edge_feats = (const float*)d_in[2];
  const float* chi_s = (const float*)d_in[3];
  const float* cutoffs = (const float*)d_in[4];
  const int* senders = (const int*)d_in[5];
  const int* receivers = (const int*)d_in[6];
  const float* W1 = (const float*)d_in[7];
  const float* b1 = (const float*)d_in[8];
  const float* W2 = (const float*)d_in[9];
  const float* b2 = (const float*)d_in[10];
  const float* Wsp = (const float*)d_in[11];
  const float* bs = (const float*)d_in[12];
  const float* Wq = (const float*)d_in[13];
  const float* Wk = (const float*)d_in[14];

  const int E = in_sizes[4];
  const int N = in_sizes[1] / 256;

  char* ws = (char*)d_ws;
  u16* W1p = (u16*)(ws + 0);
  u16* W23p = (u16*)(ws + 32768);
  u16* Wqkp = (u16*)(ws + 229376);
  float* b23 = (float*)(ws + 491520);
  u16* qk = (u16*)(ws + 524288);  // N*512 bf16
  size_t qk_end = 524288 + (size_t)N * 512 * 2;

  // decide alpha dtype by available ws
  size_t csr_bytes = align64((size_t)N * 4) * 3 + 8192 + align64(((size_t)N + 1) * 4) +
                     align64((size_t)E * 4);
  size_t need_f32 = align64(qk_end) + align64((size_t)E * 32 * 4) + csr_bytes;
  int alpha_f32 = (ws_size >= need_f32) ? 1 : 0;
  size_t alpha_bytes = (size_t)E * 32 * (alpha_f32 ? 4 : 2);

  size_t o = align64(qk_end);
  void* alpha = (void*)(ws + o);
  o = align64(o + alpha_bytes);
  int* counts = (int*)(ws + o);  // becomes exclusive partials in-place
  o += align64((size_t)N * 4);
  int* bsum = (int*)(ws + o);
  o += 4096;
  int* boff = (int*)(ws + o);
  o += 4096;
  int* off = (int*)(ws + o);
  o += align64(((size_t)N + 1) * 4);
  int* cursor = (int*)(ws + o);
  o += align64((size_t)N * 4);
  int* eid = (int*)(ws + o);

  const int nb_scan = (N + 1023) / 1024;

  (void)hipMemsetAsync(counts, 0, (size_t)N * 4, stream);
  pack_kernel<<<121, 256, 0, stream>>>(W1, W2, Wsp, Wq, Wk, b2, bs, W1p, W23p, Wqkp, b23);
  node_qk_kernel<<<(N + 63) / 64, 256, 0, stream>>>(node_feats, Wqkp, qk, N);
  hist_kernel<<<(E + 255) / 256, 256, 0, stream>>>(receivers, counts, E);
  scan_block_kernel<<<nb_scan, 256, 0, stream>>>(counts, bsum, N);
  scan_top_kernel<<<1, 64, 0, stream>>>(bsum, boff, nb_scan);
  finalize_kernel<<<(N + 255) / 256, 256, 0, stream>>>(counts, boff, off, cursor, N, E);
  fill_kernel<<<(E + 255) / 256, 256, 0, stream>>>(receivers, cursor, eid, E);
  edge_alpha_kernel<<<(E + 63) / 64, 256, 0, stream>>>(
      edge_feats, chi_s, cutoffs, senders, receivers, W1p, W23p, b1, b23, qk,
      alpha, alpha_f32, E);
  gather_out_kernel<<<(N + 3) / 4, 256, 0, stream>>>(edge_sh, alpha, off, eid,
                                                     (float*)d_out, N, alpha_f32);
}